// Round 11
// baseline (225.051 us; speedup 1.0000x reference)
//
#include <hip/hip_runtime.h>
#include <hip/hip_bf16.h>
#include <stdint.h>

#define NB 8
#define TT 2048
#define DD 1024
#define HDIM 64

typedef __bf16 bf16x8 __attribute__((ext_vector_type(8)));
typedef float f32x4 __attribute__((ext_vector_type(4)));
typedef ushort u16x4 __attribute__((ext_vector_type(4)));

static_assert(sizeof(bf16x8) == 16, "bf16x8 must be 16 bytes");

__device__ inline ushort f2bf_bits(float f) {
    __hip_bfloat16 h = __float2bfloat16(f);
    return *reinterpret_cast<ushort*>(&h);
}
__device__ inline float bfbits2f(ushort u) {
    unsigned v = ((unsigned)u) << 16;
    return __builtin_bit_cast(float, v);
}
__device__ inline bf16x8 ldb8(const ushort* p) {
    return *reinterpret_cast<const bf16x8*>(p);
}

// async global->LDS DMA, 16B/lane: dest = wave-uniform base + lane*16,
// source = per-lane address (may be arbitrarily permuted within a region).
typedef __attribute__((address_space(3))) uint32_t lds_u32;
typedef const __attribute__((address_space(1))) uint32_t glb_u32;
__device__ inline void gl_lds16(const void* g, void* l) {
    __builtin_amdgcn_global_load_lds((glb_u32*)g, (lds_u32*)l, 16, 0, 0);
}

// s_waitcnt immediates (gfx9: vm[3:0]+[15:14], exp[6:4], lgkm[11:8])
#define WCNT_VM2   0xF72   // vmcnt(2)
#define WCNT_VM5   0xF75   // vmcnt(5)
#define WCNT_LGKM0 0xC07F  // lgkmcnt(0), vmcnt/expcnt unconstrained

// ---------------------------------------------------------------------------
// Inline dtype probe: f32 x -> even halfwords show wild bf16 exponents.
// ---------------------------------------------------------------------------
__device__ inline int probe_f32(const ushort* x) {
    int lane = threadIdx.x & 63;
    int wild = 0;
    #pragma unroll
    for (int j = 0; j < 4; ++j) {
        ushort u = x[(lane * 4 + j) * 32];
        int e = (u >> 7) & 0xFF;
        wild += (e >= 0xC0);
    }
    unsigned long long m = __ballot(wild > 0);
    return __popcll(m) > 8;
}

// ---------------------------------------------------------------------------
// Kernel 1: pack weights -> Wt in DMA-READY layout: 16 k-steps x 24 frags x
// 1KB (each k_proj B-DMA reads a CONTIGUOUS 1KB block).  Also zeroes the
// per-(b,qb) merge counters (workspace is poisoned between iterations).
// Softmax scale * log2(e) folded into Wq (exp2 domain).
// ---------------------------------------------------------------------------
__global__ __launch_bounds__(256) void k_wt(const ushort* __restrict__ x,
                                            const void* __restrict__ Wq,
                                            const void* __restrict__ Wk,
                                            const void* __restrict__ Wv,
                                            ushort* __restrict__ Wt,
                                            int* __restrict__ cnt) {
    int f32m = probe_f32(x);
    int idx = blockIdx.x * 256 + threadIdx.x;   // 0 .. 196607
    if (idx < 1024) cnt[idx] = 0;               // merge counters
    int mat = idx >> 16;
    int rem = idx & 65535;                      // = d*64 + h
    int d = rem >> 6;
    int h = rem & 63;
    const void* W = (mat == 0) ? Wq : (mat == 1) ? Wk : Wv;
    float v;
    if (f32m) v = ((const float*)W)[rem];
    else      v = bfbits2f(((const ushort*)W)[rem]);
    if (mat == 0) v *= 0.18033688011112042f;    // 0.125 * log2(e)
    int n    = mat * 64 + h;                    // global out-col 0..191
    int nt   = n >> 4, ncol = n & 15;
    int kk   = d >> 6, ks = (d >> 5) & 1, qd = (d >> 3) & 3, e = d & 7;
    int f    = nt * 2 + ks;                     // 0..23
    Wt[((size_t)(kk * 24 + f)) * 512 + (qd * 16 + ncol) * 8 + e] = f2bf_bits(v);
}

// ---------------------------------------------------------------------------
// Kernel 2: QKV projection.  256 blocks x 512 threads (8 waves = 2mtw x
// 4nh); block = 64 rows x ALL 192 cols; wave = 32x48 (acc[2][3], 12
// MFMA/step).  LDS = 48KB B-double + 32KB A-double = 80KB -> 2 blocks/CU.
// B: 3 contiguous 1KB DMAs/wave/step from packed Wt; A: 2 per-lane f32x4
// loads -> cvt -> 2 u16x4 ds_writes in MFMA fragment layout.  Counted
// vmcnt(5) retires B_t, keeps A_{t+1}+B_{t+1} in flight.  (~33us,
// load-path-bound.)  V output in BLOCKED layout V2[b][t/32][d][t%32]
// (32-key tile = contiguous 4KB) with u16x4 stores.
// ---------------------------------------------------------------------------
template <int F32M>
__device__ inline void proj_body(const void* __restrict__ xv,
                                 const ushort* __restrict__ Wt,
                                 ushort* __restrict__ Qw,
                                 ushort* __restrict__ Kw,
                                 ushort* __restrict__ V2,
                                 ushort* Bf, ushort* Afb) {
    int tid  = threadIdx.x;
    int w    = tid >> 6;                 // 0..7
    int lane = tid & 63;
    int quad = lane >> 4;
    int col  = lane & 15;
    int mtw  = w >> 2;                   // 0..1 -> 32-row half (compute)
    int nh   = w & 3;                    // 0..3 -> 48-col strip
    int m0   = blockIdx.x * 64;

    const float*  xf = (const float*)xv;
    const ushort* xb = (const ushort*)xv;

    // B staging: 3 contiguous 1KB frags per wave (24/block-step).
    auto stageB = [&](int buf, int kkk) {
        int kk24 = (kkk >> 6) * 24;
        #pragma unroll
        for (int j = 0; j < 3; ++j) {
            int f = w * 3 + j;           // 0..23
            gl_lds16(Wt + ((size_t)(kk24 + f)) * 512 + lane * 8,
                     Bf + ((size_t)buf * 24 + f) * 512);
        }
    };

    // A: lane owns row m0 + w*8 + (lane>>3); two k-chunks c = (lane&7),
    // (lane&7)+8 (f32x4 each).
    int arow  = m0 + w * 8 + (lane >> 3);
    int amt_s = w >> 1;
    int colp  = (w & 1) * 8 + (lane >> 3);
    f32x4 arf[2];
    u16x4 arb[2];
    auto loadA = [&](int kkk) {
        #pragma unroll
        for (int i = 0; i < 2; ++i) {
            int c = (lane & 7) + i * 8;
            if (F32M) arf[i] = *reinterpret_cast<const f32x4*>(xf + (size_t)arow * DD + kkk + c * 4);
            else      arb[i] = *reinterpret_cast<const u16x4*>(xb + (size_t)arow * DD + kkk + c * 4);
        }
    };
    auto writeA = [&](int q) {
        #pragma unroll
        for (int i = 0; i < 2; ++i) {
            int c  = (lane & 7) + i * 8;
            int ks = i;
            int qd = (c & 7) >> 1;
            int e0 = (c & 1) * 4;
            u16x4 v;
            if (F32M) {
                #pragma unroll
                for (int j = 0; j < 4; ++j) v[j] = f2bf_bits(arf[i][j]);
            } else {
                v = arb[i];
            }
            *reinterpret_cast<u16x4*>(Afb + ((size_t)q * 16 + amt_s * 2 + ks) * 512
                                      + (qd * 16 + colp) * 8 + e0) = v;
        }
    };

    f32x4 acc[2][3];
    #pragma unroll
    for (int i = 0; i < 2; ++i)
        #pragma unroll
        for (int j = 0; j < 3; ++j) acc[i][j] = (f32x4){0.f, 0.f, 0.f, 0.f};

    // prologue: A_0 -> regs -> LDS; B_0 DMAs stay in flight past writeA's wait
    loadA(0);
    stageB(0, 0);
    writeA(0);
    __builtin_amdgcn_s_waitcnt(WCNT_LGKM0);    // A_0 ds_writes flushed

    for (int t = 0; t < 16; ++t) {
        int p   = t & 1;
        int kn1 = (t + 1 < 16) ? (t + 1) * 64 : 960;  // tail: harmless re-stage
        loadA(kn1);                            // A_{t+1} -> regs
        stageB(p ^ 1, kn1);                    // B_{t+1} -> LDS (other buffer)
        __builtin_amdgcn_s_waitcnt(WCNT_VM5);  // retire B_t(3); A+B_{t+1} fly
        __builtin_amdgcn_s_barrier();          // B_t + A_t visible block-wide

        #pragma unroll
        for (int ks = 0; ks < 2; ++ks) {
            bf16x8 a0 = ldb8(Afb + ((size_t)p * 16 + (mtw * 2 + 0) * 2 + ks) * 512 + lane * 8);
            bf16x8 a1 = ldb8(Afb + ((size_t)p * 16 + (mtw * 2 + 1) * 2 + ks) * 512 + lane * 8);
            #pragma unroll
            for (int j = 0; j < 3; ++j) {
                int nt = nh * 3 + j;
                bf16x8 b = ldb8(Bf + ((size_t)p * 24 + nt * 2 + ks) * 512 + lane * 8);
                acc[0][j] = __builtin_amdgcn_mfma_f32_16x16x32_bf16(a0, b, acc[0][j], 0, 0, 0);
                acc[1][j] = __builtin_amdgcn_mfma_f32_16x16x32_bf16(a1, b, acc[1][j], 0, 0, 0);
            }
        }
        writeA(p ^ 1);                         // A_{t+1} into other buffer
        __builtin_amdgcn_s_waitcnt(WCNT_LGKM0);
        __builtin_amdgcn_s_barrier();          // reads done; A-write flushed
    }

    // C/D layout: row = quad*4 + reg, col = lane&15
    #pragma unroll
    for (int mloc = 0; mloc < 2; ++mloc) {
        #pragma unroll
        for (int j = 0; j < 3; ++j) {
            int nt  = nh * 3 + j;
            int mat = nt >> 2;                 // 0=Q,1=K,2=V
            int h   = (nt & 3) * 16 + col;
            if (mat == 2) {
                int row0 = m0 + mtw * 32 + mloc * 16 + quad * 4;
                int bb   = row0 >> 11;
                int t0   = row0 & (TT - 1);
                u16x4 v;
                #pragma unroll
                for (int r = 0; r < 4; ++r) v[r] = f2bf_bits(acc[mloc][j][r]);
                *reinterpret_cast<u16x4*>(V2 + (size_t)bb * HDIM * TT
                                          + (size_t)(t0 >> 5) * 2048
                                          + h * 32 + (t0 & 31)) = v;
            } else {
                ushort* outp = (mat == 0) ? Qw : Kw;
                #pragma unroll
                for (int r = 0; r < 4; ++r) {
                    int row = m0 + mtw * 32 + mloc * 16 + quad * 4 + r;
                    outp[(size_t)row * HDIM + h] = f2bf_bits(acc[mloc][j][r]);
                }
            }
        }
    }
}

__global__ __launch_bounds__(512, 4) void k_proj(const void* __restrict__ xv,
                                                 const ushort* __restrict__ Wt,
                                                 ushort* __restrict__ Qw,
                                                 ushort* __restrict__ Kw,
                                                 ushort* __restrict__ V2) {
    __shared__ ushort Bf[2 * 24 * 512];        // 48 KB (double buffer)
    __shared__ ushort Afb[2 * 16 * 512];       // 32 KB (double buffer)
    if (probe_f32((const ushort*)xv)) proj_body<1>(xv, Wt, Qw, Kw, V2, Bf, Afb);
    else                              proj_body<0>(xv, Wt, Qw, Kw, V2, Bf, Afb);
}

// ---------------------------------------------------------------------------
// Kernel 3: split-K causal flash attention with CONTIGUOUS K/V staging
// (R10 body) + FUSED MERGE.  qb<32 (single-chunk): the computing wave
// normalizes its registers and writes the output directly (no Po/Pl).
// qb>=32: write chunk partials, __threadfence (release), atomicAdd on the
// per-(b,qb) counter (device scope); the last arriver __threadfence
// (acquire) and performs the merge for that qb.  Eliminates the k_merge
// dispatch + its launch gap.
// ---------------------------------------------------------------------------
__global__ __launch_bounds__(256) void k_attn(const ushort* __restrict__ xp,
                                              const ushort* __restrict__ Qw,
                                              const ushort* __restrict__ Kw,
                                              const ushort* __restrict__ V2w,
                                              ushort* __restrict__ Po,
                                              float* __restrict__ Pl,
                                              int* __restrict__ cnt,
                                              void* __restrict__ outv) {
    int f32m = probe_f32(xp);
    int w    = threadIdx.x >> 6;
    int lane = threadIdx.x & 63;
    int quad = lane >> 4;
    int col  = lane & 15;
    int bid  = blockIdx.x;               // 0..639
    int b    = bid & 7;
    int idx  = 79 - (bid >> 3);          // longer blocks earlier-ish
    int c, g;
    if (idx < 32)      { c = 0; g = idx; }
    else if (idx < 56) { c = 1; g = idx - 24; }
    else if (idx < 72) { c = 2; g = idx - 40; }
    else               { c = 3; g = idx - 48; }
    int qb = 4 * g + w;                  // this wave's q-tile
    int m0 = qb * 16;
    int nch = (qb >> 5) + 1;             // chunks for this q-tile
    int Bq = (qb < 32) ? qb : (qb < 64) ? 2*qb - 32 : (qb < 96) ? 3*qb - 96 : 4*qb - 192;
    int pid0 = b * 320 + Bq;
    int pid  = pid0 + c;

    const ushort* Qb  = Qw  + (size_t)b * TT * HDIM;
    const ushort* Kb  = Kw  + (size_t)b * TT * HDIM;
    const ushort* V2b = V2w + (size_t)b * HDIM * TT;

    __shared__ ushort KVb[2][4096];            // 16 KB: [K 2048 | V 2048] x2
    __shared__ __hip_bfloat16 Pls[4][16][40];  //  5 KB per-wave P roundtrip

    // wave w stages DMAs 2w, 2w+1.  i<4: K granules; i>=4: V granules.
    auto stageKV = [&](int buf, int s) {
        #pragma unroll
        for (int j = 0; j < 2; ++j) {
            int i = w * 2 + j;
            const ushort* gp;
            if (i < 4) {
                int row = i * 8 + (lane >> 3);             // key-in-tile 0..31
                int cg  = (lane & 7) ^ (lane >> 3);        // granule-in-row
                gp = Kb + (size_t)(s + row) * HDIM + cg * 8;
            } else {
                int w3 = (lane & 7) ^ (lane >> 3);
                int d  = (i - 4) * 16 + 2 * (lane >> 3) + (w3 >> 2);  // 0..63
                int cg = w3 & 3;
                gp = V2b + (size_t)(s >> 5) * 2048 + d * 32 + cg * 8;
            }
            gl_lds16(gp, &KVb[buf][i * 512]);
        }
    };

    // swizzled read slots (ushort offsets)
    int cb7  = col & 7;
    int vlow = (quad + 4 * (col & 1)) ^ ((col >> 1) & 7);
    auto kslot = [&](int rb, int half) {
        return ((rb + col) * 8 + ((half * 4 + quad) ^ cb7)) * 8;
    };
    auto vslot = [&](int vg) {
        return 2048 + ((vg * 8 + (col >> 1)) * 8 + vlow) * 8;
    };

    bf16x8 qf0 = ldb8(Qb + (size_t)(m0 + col) * HDIM + quad * 8);
    bf16x8 qf1 = ldb8(Qb + (size_t)(m0 + col) * HDIM + 32 + quad * 8);

    f32x4 o0 = {0.f,0.f,0.f,0.f};
    f32x4 o1 = {0.f,0.f,0.f,0.f};
    f32x4 o2 = {0.f,0.f,0.f,0.f};
    f32x4 o3 = {0.f,0.f,0.f,0.f};
    float rsum[4] = {0.f, 0.f, 0.f, 0.f};

    const int start = c * 512;
    const int end   = min(start + 512, 64 * g + 64);   // block-uniform

    stageKV(0, start);
    for (int s0 = start; s0 < end; s0 += 32) {
        int p  = ((s0 - start) >> 5) & 1;
        int sn = (s0 + 32 < end) ? s0 + 32 : s0;
        stageKV(p ^ 1, sn);
        __builtin_amdgcn_s_waitcnt(WCNT_VM2);   // own step-i DMAs done
        __builtin_amdgcn_s_barrier();           // whole buf[p] staged

        if (s0 < m0 + 16) {                     // wave-uniform causal skip
            bf16x8 ck0l = ldb8(&KVb[p][kslot(0,  0)]);
            bf16x8 ck0h = ldb8(&KVb[p][kslot(0,  1)]);
            bf16x8 ck1l = ldb8(&KVb[p][kslot(16, 0)]);
            bf16x8 ck1h = ldb8(&KVb[p][kslot(16, 1)]);

            f32x4 S0 = {0.f,0.f,0.f,0.f};
            f32x4 S1 = {0.f,0.f,0.f,0.f};
            S0 = __builtin_amdgcn_mfma_f32_16x16x32_bf16(qf0, ck0l, S0, 0, 0, 0);
            S0 = __builtin_amdgcn_mfma_f32_16x16x32_bf16(qf1, ck0h, S0, 0, 0, 0);
            S1 = __builtin_amdgcn_mfma_f32_16x16x32_bf16(qf0, ck1l, S1, 0, 0, 0);
            S1 = __builtin_amdgcn_mfma_f32_16x16x32_bf16(qf1, ck1h, S1, 0, 0, 0);

            #pragma unroll
            for (int r = 0; r < 4; ++r) {
                int trow = m0 + quad * 4 + r;
                float aa = (s0 + col      > trow) ? -1e30f : S0[r];
                float dd = (s0 + 16 + col > trow) ? -1e30f : S1[r];
                float p0 = exp2f(aa);
                float p1 = exp2f(dd);
                rsum[r] += p0 + p1;
                Pls[w][quad * 4 + r][col]      = __float2bfloat16(p0);
                Pls[w][quad * 4 + r][16 + col] = __float2bfloat16(p1);
            }
            bf16x8 pf = *reinterpret_cast<const bf16x8*>(&Pls[w][col][quad * 8]);

            bf16x8 cv0 = ldb8(&KVb[p][vslot(0)]);
            bf16x8 cv1 = ldb8(&KVb[p][vslot(1)]);
            bf16x8 cv2 = ldb8(&KVb[p][vslot(2)]);
            bf16x8 cv3 = ldb8(&KVb[p][vslot(3)]);
            o0 = __builtin_amdgcn_mfma_f32_16x16x32_bf16(pf, cv0, o0, 0, 0, 0);
            o1 = __builtin_amdgcn_mfma_f32_16x16x32_bf16(pf, cv1, o1, 0, 0, 0);
            o2 = __builtin_amdgcn_mfma_f32_16x16x32_bf16(pf, cv2, o2, 0, 0, 0);
            o3 = __builtin_amdgcn_mfma_f32_16x16x32_bf16(pf, cv3, o3, 0, 0, 0);
        }
        __builtin_amdgcn_s_waitcnt(WCNT_LGKM0); // buf[p] reads complete
        __builtin_amdgcn_s_barrier();           // before buf[p] re-stage
    }

    #pragma unroll
    for (int off = 1; off < 16; off <<= 1) {
        #pragma unroll
        for (int r = 0; r < 4; ++r)
            rsum[r] += __shfl_xor(rsum[r], off, 64);
    }

    if (nch == 1) {
        // single chunk: normalize in-register, write output directly
        size_t base = ((size_t)b * TT + (size_t)m0) * HDIM;
        #pragma unroll
        for (int r = 0; r < 4; ++r) {
            float inv = 1.0f / rsum[r];
            size_t ro = base + (size_t)(quad * 4 + r) * HDIM;
            if (f32m) {
                float* ob = (float*)outv;
                ob[ro + 0*16 + col] = o0[r] * inv;
                ob[ro + 1*16 + col] = o1[r] * inv;
                ob[ro + 2*16 + col] = o2[r] * inv;
                ob[ro + 3*16 + col] = o3[r] * inv;
            } else {
                ushort* ob = (ushort*)outv;
                ob[ro + 0*16 + col] = f2bf_bits(o0[r] * inv);
                ob[ro + 1*16 + col] = f2bf_bits(o1[r] * inv);
                ob[ro + 2*16 + col] = f2bf_bits(o2[r] * inv);
                ob[ro + 3*16 + col] = f2bf_bits(o3[r] * inv);
            }
        }
    } else {
        // write chunk partials
        ushort* pb = Po + (size_t)pid * 1024;
        #pragma unroll
        for (int r = 0; r < 4; ++r) {
            int row = quad * 4 + r;
            pb[row * 64 + 0*16 + col] = f2bf_bits(o0[r]);
            pb[row * 64 + 1*16 + col] = f2bf_bits(o1[r]);
            pb[row * 64 + 2*16 + col] = f2bf_bits(o2[r]);
            pb[row * 64 + 3*16 + col] = f2bf_bits(o3[r]);
            if (col == 0) Pl[pid * 16 + row] = rsum[r];
        }
        // release: partials visible device-wide, then count in
        __threadfence();
        int old = 0;
        if (lane == 0) old = atomicAdd(cnt + (b * 128 + qb), 1);
        old = __shfl(old, 0, 64);
        if (old == nch - 1) {
            // last arriver merges this q-tile
            __threadfence();                   // acquire
            int row = lane >> 2;
            int gs  = lane & 3;
            float L = 0.f;
            #pragma unroll
            for (int c2 = 0; c2 < 4; ++c2)
                if (c2 < nch) L += Pl[(pid0 + c2) * 16 + row];
            float inv = 1.0f / L;
            float o[16];
            #pragma unroll
            for (int j = 0; j < 16; ++j) o[j] = 0.f;
            #pragma unroll
            for (int c2 = 0; c2 < 4; ++c2) {
                if (c2 < nch) {
                    const ushort* p = Po + (size_t)(pid0 + c2) * 1024 + row * 64 + gs * 16;
                    bf16x8 v0 = ldb8(p);
                    bf16x8 v1 = ldb8(p + 8);
                    #pragma unroll
                    for (int j = 0; j < 8; ++j) {
                        o[j]     += (float)v0[j];
                        o[8 + j] += (float)v1[j];
                    }
                }
            }
            size_t obase = ((size_t)b * TT + (size_t)m0 + row) * HDIM + gs * 16;
            if (f32m) {
                float* ob = (float*)outv + obase;
                #pragma unroll
                for (int j = 0; j < 16; ++j) ob[j] = o[j] * inv;
            } else {
                ushort* ob = (ushort*)outv + obase;
                #pragma unroll
                for (int j = 0; j < 16; ++j) ob[j] = f2bf_bits(o[j] * inv);
            }
        }
    }
}

// ---------------------------------------------------------------------------
extern "C" void kernel_launch(void* const* d_in, const int* in_sizes, int n_in,
                              void* d_out, int out_size, void* d_ws, size_t ws_size,
                              hipStream_t stream) {
    const ushort* x = (const ushort*)d_in[0];
    ushort* Wt  = (ushort*)d_ws;                       // 196608 elts
    ushort* Qw  = Wt + 3 * HDIM * DD;
    ushort* Kw  = Qw + (size_t)NB * TT * HDIM;
    ushort* V2  = Kw + (size_t)NB * TT * HDIM;         // blocked V layout
    ushort* Po  = V2 + (size_t)NB * TT * HDIM;         // 2560*1024 ushorts
    float*  Pl  = (float*)(Po + (size_t)2560 * 1024);
    int*    cnt = (int*)(Pl + 2560 * 16);              // 1024 merge counters

    k_wt   <<<768, 256, 0, stream>>>(x, d_in[1], d_in[2], d_in[3], Wt, cnt);
    k_proj <<<256, 512, 0, stream>>>(d_in[0], Wt, Qw, Kw, V2);
    k_attn <<<640, 256, 0, stream>>>(x, Qw, Kw, V2, Po, Pl, cnt, d_out);
}

// Round 12
// 142.072 us; speedup vs baseline: 1.5841x; 1.5841x over previous
//
#include <hip/hip_runtime.h>
#include <hip/hip_bf16.h>
#include <stdint.h>

#define NB 8
#define TT 2048
#define DD 1024
#define HDIM 64

typedef __bf16 bf16x8 __attribute__((ext_vector_type(8)));
typedef float f32x4 __attribute__((ext_vector_type(4)));
typedef ushort u16x4 __attribute__((ext_vector_type(4)));

static_assert(sizeof(bf16x8) == 16, "bf16x8 must be 16 bytes");

__device__ inline ushort f2bf_bits(float f) {
    __hip_bfloat16 h = __float2bfloat16(f);
    return *reinterpret_cast<ushort*>(&h);
}
__device__ inline float bfbits2f(ushort u) {
    unsigned v = ((unsigned)u) << 16;
    return __builtin_bit_cast(float, v);
}
__device__ inline bf16x8 ldb8(const ushort* p) {
    return *reinterpret_cast<const bf16x8*>(p);
}

// async global->LDS DMA, 16B/lane: dest = wave-uniform base + lane*16,
// source = per-lane address (may be arbitrarily permuted within a region).
typedef __attribute__((address_space(3))) uint32_t lds_u32;
typedef const __attribute__((address_space(1))) uint32_t glb_u32;
__device__ inline void gl_lds16(const void* g, void* l) {
    __builtin_amdgcn_global_load_lds((glb_u32*)g, (lds_u32*)l, 16, 0, 0);
}

// s_waitcnt immediates (gfx9: vm[3:0]+[15:14], exp[6:4], lgkm[11:8])
#define WCNT_VM2   0xF72   // vmcnt(2)
#define WCNT_VM5   0xF75   // vmcnt(5)
#define WCNT_LGKM0 0xC07F  // lgkmcnt(0), vmcnt/expcnt unconstrained

// ---------------------------------------------------------------------------
// Inline dtype probe: f32 x -> even halfwords show wild bf16 exponents.
// ---------------------------------------------------------------------------
__device__ inline int probe_f32(const ushort* x) {
    int lane = threadIdx.x & 63;
    int wild = 0;
    #pragma unroll
    for (int j = 0; j < 4; ++j) {
        ushort u = x[(lane * 4 + j) * 32];
        int e = (u >> 7) & 0xFF;
        wild += (e >= 0xC0);
    }
    unsigned long long m = __ballot(wild > 0);
    return __popcll(m) > 8;
}

// ---------------------------------------------------------------------------
// Kernel 1: pack weights -> Wt in DMA-READY layout: 16 k-steps x 24 frags x
// 1KB (each k_proj B-DMA reads a CONTIGUOUS 1KB block).
// Softmax scale * log2(e) folded into Wq (exp2 domain).
// ---------------------------------------------------------------------------
__global__ __launch_bounds__(256) void k_wt(const ushort* __restrict__ x,
                                            const void* __restrict__ Wq,
                                            const void* __restrict__ Wk,
                                            const void* __restrict__ Wv,
                                            ushort* __restrict__ Wt) {
    int f32m = probe_f32(x);
    int idx = blockIdx.x * 256 + threadIdx.x;   // 0 .. 196607
    int mat = idx >> 16;
    int rem = idx & 65535;                      // = d*64 + h
    int d = rem >> 6;
    int h = rem & 63;
    const void* W = (mat == 0) ? Wq : (mat == 1) ? Wk : Wv;
    float v;
    if (f32m) v = ((const float*)W)[rem];
    else      v = bfbits2f(((const ushort*)W)[rem]);
    if (mat == 0) v *= 0.18033688011112042f;    // 0.125 * log2(e)
    int n    = mat * 64 + h;                    // global out-col 0..191
    int nt   = n >> 4, ncol = n & 15;
    int kk   = d >> 6, ks = (d >> 5) & 1, qd = (d >> 3) & 3, e = d & 7;
    int f    = nt * 2 + ks;                     // 0..23
    Wt[((size_t)(kk * 24 + f)) * 512 + (qd * 16 + ncol) * 8 + e] = f2bf_bits(v);
}

// ---------------------------------------------------------------------------
// Kernel 2: QKV projection.  256 blocks x 512 threads (8 waves = 2mtw x
// 4nh); block = 64 rows x ALL 192 cols; wave = 32x48 (acc[2][3], 12
// MFMA/step).  LDS = 48KB B-double + 32KB A-double = 80KB.
// B: 3 contiguous 1KB DMAs/wave/step from packed Wt; A: 2 per-lane f32x4
// loads -> cvt -> 2 u16x4 ds_writes in MFMA fragment layout.  Counted
// vmcnt(5) retires B_t, keeps A_{t+1}+B_{t+1} in flight.  (~33us,
// load-path-bound.)  V output in BLOCKED layout V2[b][t/32][d][t%32]
// (32-key tile = contiguous 4KB) with u16x4 stores.
// ---------------------------------------------------------------------------
template <int F32M>
__device__ inline void proj_body(const void* __restrict__ xv,
                                 const ushort* __restrict__ Wt,
                                 ushort* __restrict__ Qw,
                                 ushort* __restrict__ Kw,
                                 ushort* __restrict__ V2,
                                 ushort* Bf, ushort* Afb) {
    int tid  = threadIdx.x;
    int w    = tid >> 6;                 // 0..7
    int lane = tid & 63;
    int quad = lane >> 4;
    int col  = lane & 15;
    int mtw  = w >> 2;                   // 0..1 -> 32-row half (compute)
    int nh   = w & 3;                    // 0..3 -> 48-col strip
    int m0   = blockIdx.x * 64;

    const float*  xf = (const float*)xv;
    const ushort* xb = (const ushort*)xv;

    // B staging: 3 contiguous 1KB frags per wave (24/block-step).
    auto stageB = [&](int buf, int kkk) {
        int kk24 = (kkk >> 6) * 24;
        #pragma unroll
        for (int j = 0; j < 3; ++j) {
            int f = w * 3 + j;           // 0..23
            gl_lds16(Wt + ((size_t)(kk24 + f)) * 512 + lane * 8,
                     Bf + ((size_t)buf * 24 + f) * 512);
        }
    };

    // A: lane owns row m0 + w*8 + (lane>>3); two k-chunks c = (lane&7),
    // (lane&7)+8 (f32x4 each).
    int arow  = m0 + w * 8 + (lane >> 3);
    int amt_s = w >> 1;
    int colp  = (w & 1) * 8 + (lane >> 3);
    f32x4 arf[2];
    u16x4 arb[2];
    auto loadA = [&](int kkk) {
        #pragma unroll
        for (int i = 0; i < 2; ++i) {
            int c = (lane & 7) + i * 8;
            if (F32M) arf[i] = *reinterpret_cast<const f32x4*>(xf + (size_t)arow * DD + kkk + c * 4);
            else      arb[i] = *reinterpret_cast<const u16x4*>(xb + (size_t)arow * DD + kkk + c * 4);
        }
    };
    auto writeA = [&](int q) {
        #pragma unroll
        for (int i = 0; i < 2; ++i) {
            int c  = (lane & 7) + i * 8;
            int ks = i;
            int qd = (c & 7) >> 1;
            int e0 = (c & 1) * 4;
            u16x4 v;
            if (F32M) {
                #pragma unroll
                for (int j = 0; j < 4; ++j) v[j] = f2bf_bits(arf[i][j]);
            } else {
                v = arb[i];
            }
            *reinterpret_cast<u16x4*>(Afb + ((size_t)q * 16 + amt_s * 2 + ks) * 512
                                      + (qd * 16 + colp) * 8 + e0) = v;
        }
    };

    f32x4 acc[2][3];
    #pragma unroll
    for (int i = 0; i < 2; ++i)
        #pragma unroll
        for (int j = 0; j < 3; ++j) acc[i][j] = (f32x4){0.f, 0.f, 0.f, 0.f};

    // prologue: A_0 -> regs -> LDS; B_0 DMAs stay in flight past writeA's wait
    loadA(0);
    stageB(0, 0);
    writeA(0);
    __builtin_amdgcn_s_waitcnt(WCNT_LGKM0);    // A_0 ds_writes flushed

    for (int t = 0; t < 16; ++t) {
        int p   = t & 1;
        int kn1 = (t + 1 < 16) ? (t + 1) * 64 : 960;  // tail: harmless re-stage
        loadA(kn1);                            // A_{t+1} -> regs
        stageB(p ^ 1, kn1);                    // B_{t+1} -> LDS (other buffer)
        __builtin_amdgcn_s_waitcnt(WCNT_VM5);  // retire B_t(3); A+B_{t+1} fly
        __builtin_amdgcn_s_barrier();          // B_t + A_t visible block-wide

        #pragma unroll
        for (int ks = 0; ks < 2; ++ks) {
            bf16x8 a0 = ldb8(Afb + ((size_t)p * 16 + (mtw * 2 + 0) * 2 + ks) * 512 + lane * 8);
            bf16x8 a1 = ldb8(Afb + ((size_t)p * 16 + (mtw * 2 + 1) * 2 + ks) * 512 + lane * 8);
            #pragma unroll
            for (int j = 0; j < 3; ++j) {
                int nt = nh * 3 + j;
                bf16x8 b = ldb8(Bf + ((size_t)p * 24 + nt * 2 + ks) * 512 + lane * 8);
                acc[0][j] = __builtin_amdgcn_mfma_f32_16x16x32_bf16(a0, b, acc[0][j], 0, 0, 0);
                acc[1][j] = __builtin_amdgcn_mfma_f32_16x16x32_bf16(a1, b, acc[1][j], 0, 0, 0);
            }
        }
        writeA(p ^ 1);                         // A_{t+1} into other buffer
        __builtin_amdgcn_s_waitcnt(WCNT_LGKM0);
        __builtin_amdgcn_s_barrier();          // reads done; A-write flushed
    }

    // C/D layout: row = quad*4 + reg, col = lane&15
    #pragma unroll
    for (int mloc = 0; mloc < 2; ++mloc) {
        #pragma unroll
        for (int j = 0; j < 3; ++j) {
            int nt  = nh * 3 + j;
            int mat = nt >> 2;                 // 0=Q,1=K,2=V
            int h   = (nt & 3) * 16 + col;
            if (mat == 2) {
                int row0 = m0 + mtw * 32 + mloc * 16 + quad * 4;
                int bb   = row0 >> 11;
                int t0   = row0 & (TT - 1);
                u16x4 v;
                #pragma unroll
                for (int r = 0; r < 4; ++r) v[r] = f2bf_bits(acc[mloc][j][r]);
                *reinterpret_cast<u16x4*>(V2 + (size_t)bb * HDIM * TT
                                          + (size_t)(t0 >> 5) * 2048
                                          + h * 32 + (t0 & 31)) = v;
            } else {
                ushort* outp = (mat == 0) ? Qw : Kw;
                #pragma unroll
                for (int r = 0; r < 4; ++r) {
                    int row = m0 + mtw * 32 + mloc * 16 + quad * 4 + r;
                    outp[(size_t)row * HDIM + h] = f2bf_bits(acc[mloc][j][r]);
                }
            }
        }
    }
}

__global__ __launch_bounds__(512, 4) void k_proj(const void* __restrict__ xv,
                                                 const ushort* __restrict__ Wt,
                                                 ushort* __restrict__ Qw,
                                                 ushort* __restrict__ Kw,
                                                 ushort* __restrict__ V2) {
    __shared__ ushort Bf[2 * 24 * 512];        // 48 KB (double buffer)
    __shared__ ushort Afb[2 * 16 * 512];       // 32 KB (double buffer)
    if (probe_f32((const ushort*)xv)) proj_body<1>(xv, Wt, Qw, Kw, V2, Bf, Afb);
    else                              proj_body<0>(xv, Wt, Qw, Kw, V2, Bf, Afb);
}

// ---------------------------------------------------------------------------
// Kernel 3: split-K causal flash attention with CONTIGUOUS K/V staging.
// R0 loop/compute body; DMA sources and LDS addressing per R10.  Per step
// the block stages one 4KB K-tile (32 rows of plain Kw -> 4 contiguous-
// region DMAs) and one 4KB V-tile (blocked V2 -> 4 DMAs): 128 CONTIGUOUS
// 64B lines/step.  Per-lane XOR-permuted sources keep the ds_read_b128
// granule-slots uniform mod 8 => bank-conflict-free reads.  LDS 21 KB,
// 640 blocks.  (R11's fused merge with per-wave device-scope fences was a
// 3x regression -- reverted; k_merge stays a separate dispatch.)
// ---------------------------------------------------------------------------
__global__ __launch_bounds__(256) void k_attn(const ushort* __restrict__ Qw,
                                              const ushort* __restrict__ Kw,
                                              const ushort* __restrict__ V2w,
                                              ushort* __restrict__ Po,
                                              float* __restrict__ Pl) {
    int w    = threadIdx.x >> 6;
    int lane = threadIdx.x & 63;
    int quad = lane >> 4;
    int col  = lane & 15;
    int bid  = blockIdx.x;               // 0..639
    int b    = bid & 7;
    int idx  = 79 - (bid >> 3);          // longer blocks earlier-ish
    int c, g;
    if (idx < 32)      { c = 0; g = idx; }
    else if (idx < 56) { c = 1; g = idx - 24; }
    else if (idx < 72) { c = 2; g = idx - 40; }
    else               { c = 3; g = idx - 48; }
    int qb = 4 * g + w;                  // this wave's q-tile
    int m0 = qb * 16;
    int Bq = (qb < 32) ? qb : (qb < 64) ? 2*qb - 32 : (qb < 96) ? 3*qb - 96 : 4*qb - 192;
    int pid = b * 320 + Bq + c;

    const ushort* Qb  = Qw  + (size_t)b * TT * HDIM;
    const ushort* Kb  = Kw  + (size_t)b * TT * HDIM;
    const ushort* V2b = V2w + (size_t)b * HDIM * TT;

    __shared__ ushort KVb[2][4096];            // 16 KB: [K 2048 | V 2048] x2
    __shared__ __hip_bfloat16 Pls[4][16][40];  //  5 KB per-wave P roundtrip

    // wave w stages DMAs 2w, 2w+1.  i<4: K granules; i>=4: V granules.
    // dest = KVb[buf] + i*512 ushorts (linear, lane*16B); src per-lane
    // permuted within the contiguous 4KB tile.
    auto stageKV = [&](int buf, int s) {
        #pragma unroll
        for (int j = 0; j < 2; ++j) {
            int i = w * 2 + j;
            const ushort* gp;
            if (i < 4) {
                int row = i * 8 + (lane >> 3);             // key-in-tile 0..31
                int cg  = (lane & 7) ^ (lane >> 3);        // granule-in-row
                gp = Kb + (size_t)(s + row) * HDIM + cg * 8;
            } else {
                int w3 = (lane & 7) ^ (lane >> 3);
                int d  = (i - 4) * 16 + 2 * (lane >> 3) + (w3 >> 2);  // 0..63
                int cg = w3 & 3;
                gp = V2b + (size_t)(s >> 5) * 2048 + d * 32 + cg * 8;
            }
            gl_lds16(gp, &KVb[buf][i * 512]);
        }
    };

    // swizzled read slots (ushort offsets)
    int cb7  = col & 7;
    int vlow = (quad + 4 * (col & 1)) ^ ((col >> 1) & 7);
    auto kslot = [&](int rb, int half) {
        return ((rb + col) * 8 + ((half * 4 + quad) ^ cb7)) * 8;
    };
    auto vslot = [&](int vg) {
        return 2048 + ((vg * 8 + (col >> 1)) * 8 + vlow) * 8;
    };

    bf16x8 qf0 = ldb8(Qb + (size_t)(m0 + col) * HDIM + quad * 8);
    bf16x8 qf1 = ldb8(Qb + (size_t)(m0 + col) * HDIM + 32 + quad * 8);

    f32x4 o0 = {0.f,0.f,0.f,0.f};
    f32x4 o1 = {0.f,0.f,0.f,0.f};
    f32x4 o2 = {0.f,0.f,0.f,0.f};
    f32x4 o3 = {0.f,0.f,0.f,0.f};
    float rsum[4] = {0.f, 0.f, 0.f, 0.f};

    const int start = c * 512;
    const int end   = min(start + 512, 64 * g + 64);   // block-uniform

    stageKV(0, start);
    for (int s0 = start; s0 < end; s0 += 32) {
        int p  = ((s0 - start) >> 5) & 1;
        int sn = (s0 + 32 < end) ? s0 + 32 : s0;
        stageKV(p ^ 1, sn);
        __builtin_amdgcn_s_waitcnt(WCNT_VM2);   // own step-i DMAs done
        __builtin_amdgcn_s_barrier();           // whole buf[p] staged

        if (s0 < m0 + 16) {                     // wave-uniform causal skip
            bf16x8 ck0l = ldb8(&KVb[p][kslot(0,  0)]);
            bf16x8 ck0h = ldb8(&KVb[p][kslot(0,  1)]);
            bf16x8 ck1l = ldb8(&KVb[p][kslot(16, 0)]);
            bf16x8 ck1h = ldb8(&KVb[p][kslot(16, 1)]);

            f32x4 S0 = {0.f,0.f,0.f,0.f};
            f32x4 S1 = {0.f,0.f,0.f,0.f};
            S0 = __builtin_amdgcn_mfma_f32_16x16x32_bf16(qf0, ck0l, S0, 0, 0, 0);
            S0 = __builtin_amdgcn_mfma_f32_16x16x32_bf16(qf1, ck0h, S0, 0, 0, 0);
            S1 = __builtin_amdgcn_mfma_f32_16x16x32_bf16(qf0, ck1l, S1, 0, 0, 0);
            S1 = __builtin_amdgcn_mfma_f32_16x16x32_bf16(qf1, ck1h, S1, 0, 0, 0);

            #pragma unroll
            for (int r = 0; r < 4; ++r) {
                int trow = m0 + quad * 4 + r;
                float aa = (s0 + col      > trow) ? -1e30f : S0[r];
                float dd = (s0 + 16 + col > trow) ? -1e30f : S1[r];
                float p0 = exp2f(aa);
                float p1 = exp2f(dd);
                rsum[r] += p0 + p1;
                Pls[w][quad * 4 + r][col]      = __float2bfloat16(p0);
                Pls[w][quad * 4 + r][16 + col] = __float2bfloat16(p1);
            }
            bf16x8 pf = *reinterpret_cast<const bf16x8*>(&Pls[w][col][quad * 8]);

            bf16x8 cv0 = ldb8(&KVb[p][vslot(0)]);
            bf16x8 cv1 = ldb8(&KVb[p][vslot(1)]);
            bf16x8 cv2 = ldb8(&KVb[p][vslot(2)]);
            bf16x8 cv3 = ldb8(&KVb[p][vslot(3)]);
            o0 = __builtin_amdgcn_mfma_f32_16x16x32_bf16(pf, cv0, o0, 0, 0, 0);
            o1 = __builtin_amdgcn_mfma_f32_16x16x32_bf16(pf, cv1, o1, 0, 0, 0);
            o2 = __builtin_amdgcn_mfma_f32_16x16x32_bf16(pf, cv2, o2, 0, 0, 0);
            o3 = __builtin_amdgcn_mfma_f32_16x16x32_bf16(pf, cv3, o3, 0, 0, 0);
        }
        __builtin_amdgcn_s_waitcnt(WCNT_LGKM0); // buf[p] reads complete
        __builtin_amdgcn_s_barrier();           // before buf[p] re-stage
    }

    #pragma unroll
    for (int off = 1; off < 16; off <<= 1) {
        #pragma unroll
        for (int r = 0; r < 4; ++r)
            rsum[r] += __shfl_xor(rsum[r], off, 64);
    }

    ushort* pb = Po + (size_t)pid * 1024;
    #pragma unroll
    for (int r = 0; r < 4; ++r) {
        int row = quad * 4 + r;
        pb[row * 64 + 0*16 + col] = f2bf_bits(o0[r]);
        pb[row * 64 + 1*16 + col] = f2bf_bits(o1[r]);
        pb[row * 64 + 2*16 + col] = f2bf_bits(o2[r]);
        pb[row * 64 + 3*16 + col] = f2bf_bits(o3[r]);
        if (col == 0) Pl[pid * 16 + row] = rsum[r];
    }
}

// ---------------------------------------------------------------------------
// Kernel 4: merge <=4 chunk partials (plain sum, shared implicit max=0),
// normalize by total L, store out.  One wave per (b,qb).
// ---------------------------------------------------------------------------
__global__ __launch_bounds__(256) void k_merge(const ushort* __restrict__ x,
                                               const ushort* __restrict__ Po,
                                               const float* __restrict__ Pl,
                                               void* __restrict__ outv) {
    int f32m = probe_f32(x);
    int wid  = blockIdx.x * 4 + (threadIdx.x >> 6);  // 0..1023
    int lane = threadIdx.x & 63;
    int row  = lane >> 2;
    int g    = lane & 3;
    int b    = wid >> 7;
    int qb   = wid & 127;
    int nch  = (qb >> 5) + 1;
    int Bq   = (qb < 32) ? qb : (qb < 64) ? 2*qb - 32 : (qb < 96) ? 3*qb - 96 : 4*qb - 192;
    int pid0 = b * 320 + Bq;

    float L = 0.f;
    #pragma unroll
    for (int c = 0; c < 4; ++c)
        if (c < nch) L += Pl[(pid0 + c) * 16 + row];
    float inv = 1.0f / L;

    float o[16];
    #pragma unroll
    for (int j = 0; j < 16; ++j) o[j] = 0.f;
    #pragma unroll
    for (int c = 0; c < 4; ++c) {
        if (c < nch) {
            const ushort* p = Po + (size_t)(pid0 + c) * 1024 + row * 64 + g * 16;
            bf16x8 v0 = ldb8(p);
            bf16x8 v1 = ldb8(p + 8);
            #pragma unroll
            for (int j = 0; j < 8; ++j) {
                o[j]     += (float)v0[j];
                o[8 + j] += (float)v1[j];
            }
        }
    }

    size_t obase = ((size_t)b * TT + qb * 16 + row) * HDIM + g * 16;
    if (f32m) {
        float* ob = (float*)outv + obase;
        #pragma unroll
        for (int j = 0; j < 16; ++j) ob[j] = o[j] * inv;
    } else {
        ushort* ob = (ushort*)outv + obase;
        #pragma unroll
        for (int j = 0; j < 16; ++j) ob[j] = f2bf_bits(o[j] * inv);
    }
}

// ---------------------------------------------------------------------------
extern "C" void kernel_launch(void* const* d_in, const int* in_sizes, int n_in,
                              void* d_out, int out_size, void* d_ws, size_t ws_size,
                              hipStream_t stream) {
    const ushort* x = (const ushort*)d_in[0];
    ushort* Wt  = (ushort*)d_ws;                       // 196608 elts
    ushort* Qw  = Wt + 3 * HDIM * DD;
    ushort* Kw  = Qw + (size_t)NB * TT * HDIM;
    ushort* V2  = Kw + (size_t)NB * TT * HDIM;         // blocked V layout
    ushort* Po  = V2 + (size_t)NB * TT * HDIM;         // 2560*1024 ushorts
    float*  Pl  = (float*)(Po + (size_t)2560 * 1024);  // ~12.2 MB total

    k_wt   <<<768, 256, 0, stream>>>(x, d_in[1], d_in[2], d_in[3], Wt);
    k_proj <<<256, 512, 0, stream>>>(d_in[0], Wt, Qw, Kw, V2);
    k_attn <<<640, 256, 0, stream>>>(Qw, Kw, V2, Po, Pl);
    k_merge<<<256, 256, 0, stream>>>(x, Po, Pl, d_out);
}